// Round 1
// baseline (436.043 us; speedup 1.0000x reference)
//
#include <hip/hip_runtime.h>
#include <cstdint>
#include <cstddef>

#define N_NODES 8192
#define IN_DIM  256
#define OUT_DIM 64
#define HEADS   2
#define FEAT    128           // OUT_DIM*HEADS
#define NTILES  9             // 144 B-cols: 128 feat + 2 denom + 14 pad
#define ACC_STRIDE 132
#define KSPLIT  4

typedef __bf16 bf16x8 __attribute__((ext_vector_type(8)));
typedef float  f32x4  __attribute__((ext_vector_type(4)));

static __device__ __forceinline__ unsigned short f2bf(float f) {
  unsigned u = __float_as_uint(f);
  u += 0x7FFFu + ((u >> 16) & 1u);     // round-to-nearest-even
  return (unsigned short)(u >> 16);
}

// ---------------------------------------------------------------- k_vr
// vr[h][k] = sum_d attn_r[h][d] * W[h*64+d][k]   (2x256)
__global__ void k_vr(const float* __restrict__ W, const float* __restrict__ attn_r,
                     float* __restrict__ vr) {
  const int t = threadIdx.x;               // 512 threads
  const int h = t >> 8, k = t & 255;
  float s = 0.f;
  for (int d = 0; d < OUT_DIM; d++)
    s += attn_r[h*OUT_DIM + d] * W[(size_t)(h*OUT_DIM + d)*IN_DIM + k];
  vr[h*IN_DIM + k] = s;
}

// ---------------------------------------------------------------- k_h
// H = x @ W^T  (fp32, 8192x128). 256 blocks: 64-row x 64-col tiles.
__global__ __launch_bounds__(256) void k_h(const float* __restrict__ x,
                                           const float* __restrict__ W,
                                           float* __restrict__ H) {
  const int rb = blockIdx.x >> 1, cb = blockIdx.x & 1;
  __shared__ float xs[32][68];   // [k][row] padded
  __shared__ float wl[32][68];   // [k][col] padded
  const int tid = threadIdx.x;
  const int ty = tid >> 4, tx = tid & 15;
  float acc[4][4] = {};
  for (int kc = 0; kc < IN_DIM; kc += 32) {
    __syncthreads();
    {
      const int r = tid >> 3, kk = (tid & 7) * 4;
      float4 xv = *(const float4*)(x + (size_t)(rb*64 + r)*IN_DIM + kc + kk);
      xs[kk+0][r] = xv.x; xs[kk+1][r] = xv.y; xs[kk+2][r] = xv.z; xs[kk+3][r] = xv.w;
      float4 xv2 = *(const float4*)(x + (size_t)(rb*64 + r + 32)*IN_DIM + kc + kk);
      xs[kk+0][r+32] = xv2.x; xs[kk+1][r+32] = xv2.y; xs[kk+2][r+32] = xv2.z; xs[kk+3][r+32] = xv2.w;
      float4 wv = *(const float4*)(W + (size_t)(cb*64 + r)*IN_DIM + kc + kk);
      wl[kk+0][r] = wv.x; wl[kk+1][r] = wv.y; wl[kk+2][r] = wv.z; wl[kk+3][r] = wv.w;
      float4 wv2 = *(const float4*)(W + (size_t)(cb*64 + r + 32)*IN_DIM + kc + kk);
      wl[kk+0][r+32] = wv2.x; wl[kk+1][r+32] = wv2.y; wl[kk+2][r+32] = wv2.z; wl[kk+3][r+32] = wv2.w;
    }
    __syncthreads();
#pragma unroll
    for (int k = 0; k < 32; k++) {
      float xr[4], wr[4];
#pragma unroll
      for (int i = 0; i < 4; i++) { xr[i] = xs[k][ty + i*16]; wr[i] = wl[k][tx + i*16]; }
#pragma unroll
      for (int i = 0; i < 4; i++)
#pragma unroll
        for (int j = 0; j < 4; j++) acc[i][j] = fmaf(xr[i], wr[j], acc[i][j]);
    }
  }
#pragma unroll
  for (int i = 0; i < 4; i++)
#pragma unroll
    for (int j = 0; j < 4; j++)
      H[(size_t)(rb*64 + ty + i*16)*FEAT + cb*64 + tx + j*16] = acc[i][j];
}

// ---------------------------------------------------------------- k_er
// er[j][h] = dot(x[j,:], vr[h,:])  fp32-exact path feeding exp()
__global__ void k_er(const float* __restrict__ x, const float* __restrict__ vr,
                     float* __restrict__ er) {
  const int wave = threadIdx.x >> 6, lane = threadIdx.x & 63;
  const int j = blockIdx.x*4 + wave;
  float4 xv = ((const float4*)(x + (size_t)j*IN_DIM))[lane];
  float4 a0 = ((const float4*)vr)[lane];
  float4 a1 = ((const float4*)(vr + IN_DIM))[lane];
  float s0 = xv.x*a0.x + xv.y*a0.y + xv.z*a0.z + xv.w*a0.w;
  float s1 = xv.x*a1.x + xv.y*a1.y + xv.z*a1.z + xv.w*a1.w;
#pragma unroll
  for (int off = 32; off > 0; off >>= 1) {
    s0 += __shfl_down(s0, off);
    s1 += __shfl_down(s1, off);
  }
  if (lane == 0) { er[j*2+0] = s0; er[j*2+1] = s1; }
}

// ---------------------------------------------------------------- k_pack
// Build fragment-ordered bf16 B: frag[kstep][n][lane][j8]
//   value = B[k = kstep*32 + (lane>>4)*8 + j][col = n*16 + (lane&15)]
//   B[j][c] = exp(er[j][c>>6]) * H[j][c]  (c<128) ; exp(er[j][c-128]) (c in 128..129); 0 pad
__global__ void k_pack(const float* __restrict__ H, const float* __restrict__ er,
                       unsigned short* __restrict__ frag) {
  const int oct = blockIdx.x;          // j-octet, 0..1023
  const int c = threadIdx.x;           // 0..191, active < 144
  if (c >= 144) return;
  const int j0 = oct * 8;
  const int kb = oct >> 2, sub = oct & 3;
  unsigned short v[8];
  if (c < FEAT) {
    const int h = c >> 6;
#pragma unroll
    for (int t = 0; t < 8; t++) {
      float w = __expf(er[(j0 + t)*2 + h]);
      v[t] = f2bf(w * H[(size_t)(j0 + t)*FEAT + c]);
    }
  } else if (c < FEAT + HEADS) {
    const int h = c - FEAT;
#pragma unroll
    for (int t = 0; t < 8; t++) v[t] = f2bf(__expf(er[(j0 + t)*2 + h]));
  } else {
#pragma unroll
    for (int t = 0; t < 8; t++) v[t] = 0;
  }
  uint4 o;
  o.x = (unsigned)v[0] | ((unsigned)v[1] << 16);
  o.y = (unsigned)v[2] | ((unsigned)v[3] << 16);
  o.z = (unsigned)v[4] | ((unsigned)v[5] << 16);
  o.w = (unsigned)v[6] | ((unsigned)v[7] << 16);
  uint4* dst = (uint4*)frag + ((size_t)(kb*NTILES + (c >> 4)))*64 + (sub*16 + (c & 15));
  *dst = o;
}

// ---------------------------------------------------------------- k_zero
__global__ void k_zero(float* __restrict__ p) {
  const int total = N_NODES * ACC_STRIDE / 4;
  for (int i = blockIdx.x*blockDim.x + threadIdx.x; i < total; i += gridDim.x*blockDim.x)
    ((float4*)p)[i] = (float4){0.f, 0.f, 0.f, 0.f};
}

// ---------------------------------------------------------------- k_main
// accum[8192][132] += adj[8192x8192] @ B[8192x144] (bf16 MFMA, fp32 acc)
// Grid 512 = 128 M-blocks x 4 K-splits. Block: 4 waves, 64 rows, 144 cols.
__global__ __launch_bounds__(256, 2) void k_main(const int* __restrict__ adj,
                                                 const uint4* __restrict__ fragB,
                                                 float* __restrict__ accum) {
  const int bx = blockIdx.x;
  const int mb = bx >> 2;                 // 0..127
  const int ks = bx & 3;                  // 0..3
  const int tid = threadIdx.x;
  const int wave = tid >> 6, lane = tid & 63;
  const int m16 = lane & 15, quad = lane >> 4;
  const int rowA = mb*64 + wave*16 + m16;

  __shared__ uint4 ldsB[2][36*64];        // 2 x 36 KB (4 ksteps x 9 ntiles x 1 KB)

  f32x4 dacc[NTILES];
#pragma unroll
  for (int n = 0; n < NTILES; n++) dacc[n] = (f32x4){0.f, 0.f, 0.f, 0.f};

  const int* abase = adj + (size_t)rowA*N_NODES + ks*2048 + quad*8;

  // wave w stages kstep-local w of each 4-kstep chunk: 9 contiguous 1 KB blocks
  auto stageB = [&](int c, int buf) {
    const uint4* src = fragB + ((size_t)(ks*64 + c*4 + wave) * NTILES) * 64 + lane;
    uint4* dst = &ldsB[buf][(wave*NTILES)*64 + lane];
#pragma unroll
    for (int t = 0; t < NTILES; t++)
      __builtin_amdgcn_global_load_lds(
          (__attribute__((address_space(1))) void*)(src + t*64),
          (__attribute__((address_space(3))) void*)(dst + t*64), 16, 0, 0);
  };

  auto prefA = [&](int c, int4 (&A)[8]) {
#pragma unroll
    for (int kl = 0; kl < 4; kl++) {
      const int* p = abase + (c*4 + kl)*32;
      A[kl*2+0] = *(const int4*)(p);
      A[kl*2+1] = *(const int4*)(p + 4);
    }
  };

  auto compute = [&](int buf, int4 (&A)[8]) {
    const uint4* lb = &ldsB[buf][0];
#pragma unroll
    for (int kl = 0; kl < 4; kl++) {
      const int* ai = (const int*)(&A[kl*2]);
      unsigned u0 = (ai[0] ? 0x3F80u : 0u) | (ai[1] ? 0x3F800000u : 0u);
      unsigned u1 = (ai[2] ? 0x3F80u : 0u) | (ai[3] ? 0x3F800000u : 0u);
      unsigned u2 = (ai[4] ? 0x3F80u : 0u) | (ai[5] ? 0x3F800000u : 0u);
      unsigned u3 = (ai[6] ? 0x3F80u : 0u) | (ai[7] ? 0x3F800000u : 0u);
      bf16x8 af = __builtin_bit_cast(bf16x8, make_uint4(u0, u1, u2, u3));
#pragma unroll
      for (int n = 0; n < NTILES; n++) {
        bf16x8 bfr = __builtin_bit_cast(bf16x8, lb[(kl*NTILES + n)*64 + lane]);
        dacc[n] = __builtin_amdgcn_mfma_f32_16x16x32_bf16(af, bfr, dacc[n], 0, 0, 0);
      }
    }
  };

  int4 A0[8], A1[8];
  prefA(0, A0);
  stageB(0, 0);
#pragma unroll
  for (int cc = 0; cc < 8; cc++) {
    __syncthreads();                       // drains chunk 2cc loads (vmcnt)
    stageB(2*cc + 1, 1);
    prefA(2*cc + 1, A1);
    compute(0, A0);                        // overlaps chunk 2cc+1 loads
    __syncthreads();                       // drains chunk 2cc+1 loads
    if (cc < 7) { stageB(2*cc + 2, 0); prefA(2*cc + 2, A0); }
    compute(1, A1);
  }

  // epilogue: C/D layout col=lane&15, row=quad*4+reg
  const int rb = mb*64 + wave*16 + quad*4;
#pragma unroll
  for (int n = 0; n < NTILES; n++) {
    if (n == 8 && m16 >= HEADS) continue;  // cols 130..143 are padding
#pragma unroll
    for (int r = 0; r < 4; r++)
      atomicAdd(&accum[(size_t)(rb + r)*ACC_STRIDE + n*16 + m16], dacc[n][r]);
  }
}

// ---------------------------------------------------------------- k_div
__global__ void k_div(const float* __restrict__ acc, float* __restrict__ out) {
  const int i = blockIdx.x, c = threadIdx.x;
  const float d = acc[(size_t)i*ACC_STRIDE + FEAT + (c >> 6)];
  out[(size_t)i*FEAT + c] = acc[(size_t)i*ACC_STRIDE + c] / d;
}

// ---------------------------------------------------------------- launch
extern "C" void kernel_launch(void* const* d_in, const int* in_sizes, int n_in,
                              void* d_out, int out_size, void* d_ws, size_t ws_size,
                              hipStream_t stream) {
  const float* x      = (const float*)d_in[0];
  const int*   adj    = (const int*)  d_in[1];
  const float* W      = (const float*)d_in[2];
  // d_in[3] = attn_l: cancels in softmax over j — unused.
  const float* attn_r = (const float*)d_in[4];

  char* ws = (char*)d_ws;
  float* vr            = (float*)(ws + 0);            // 2 KB
  float* er            = (float*)(ws + 4096);         // 64 KB
  float* H             = (float*)(ws + 131072);       // 4 MB
  unsigned short* frag = (unsigned short*)(ws + 4325376);  // 2.25 MB
  float* acc           = (float*)(ws + 6684672);      // 4.33 MB
  float* out           = (float*)d_out;

  hipLaunchKernelGGL(k_vr,   dim3(1),    dim3(512), 0, stream, W, attn_r, vr);
  hipLaunchKernelGGL(k_h,    dim3(256),  dim3(256), 0, stream, x, W, H);
  hipLaunchKernelGGL(k_er,   dim3(2048), dim3(256), 0, stream, x, vr, er);
  hipLaunchKernelGGL(k_pack, dim3(1024), dim3(192), 0, stream, H, er, frag);
  hipLaunchKernelGGL(k_zero, dim3(512),  dim3(256), 0, stream, acc);
  hipLaunchKernelGGL(k_main, dim3(512),  dim3(256), 0, stream, adj, (const uint4*)frag, acc);
  hipLaunchKernelGGL(k_div,  dim3(8192), dim3(128), 0, stream, acc, out);
}